// Round 1
// baseline (1767.728 us; speedup 1.0000x reference)
//
#include <hip/hip_runtime.h>
#include <cstdint>
#include <cstddef>

// ---------------- problem constants ----------------
constexpr int NNODES = 50000;
constexpr int NEDGES = 500000;
constexpr int NRELS  = 8;
constexpr int DIM    = 128;   // input/output dim
constexpr int ADIM   = 64;    // attention dim
constexpr int TWOD   = 256;   // 2*DIM
constexpr int EPB    = 64;    // edges per block in gate kernel
constexpr float SLOPE = 0.01f; // leaky_relu default slope

// monotone float->uint encoding for atomicMax on floats
__device__ __forceinline__ unsigned enc_f(float f) {
    unsigned u = __float_as_uint(f);
    return (u & 0x80000000u) ? ~u : (u | 0x80000000u);
}
__device__ __forceinline__ float dec_f(unsigned k) {
    unsigned u = (k & 0x80000000u) ? (k & 0x7FFFFFFFu) : ~k;
    return __uint_as_float(u);
}

// ---------------- init: zero h_N/denom/counters, smax=0-key, sorted=-1 ----------------
__global__ void k_init(float* __restrict__ hN, float* __restrict__ denom,
                       unsigned* __restrict__ smax_u, int* __restrict__ sorted,
                       int* __restrict__ cnts /*16 ints: cnt[8]+cursor[8]*/) {
    int i = blockIdx.x * blockDim.x + threadIdx.x;
    int stride = gridDim.x * blockDim.x;
    for (int idx = i; idx < NNODES * DIM; idx += stride) hN[idx] = 0.0f;
    for (int idx = i; idx < NNODES; idx += stride) { denom[idx] = 0.0f; smax_u[idx] = 0u; }
    for (int idx = i; idx < NEDGES + 1024; idx += stride) sorted[idx] = -1;
    if (i < 16) cnts[i] = 0;
}

// ---------------- counting sort by etype ----------------
__global__ void k_count(const int* __restrict__ ety, int* __restrict__ cnt) {
    __shared__ int hist[NRELS];
    int t = threadIdx.x;
    if (t < NRELS) hist[t] = 0;
    __syncthreads();
    int e = blockIdx.x * 256 + t;
    if (e < NEDGES) atomicAdd(&hist[ety[e]], 1);
    __syncthreads();
    if (t < NRELS && hist[t] > 0) atomicAdd(&cnt[t], hist[t]);
}

__global__ void k_prefix(const int* __restrict__ cnt, int* __restrict__ offs) {
    if (blockIdx.x == 0 && threadIdx.x == 0) {
        int off = 0;
        for (int r = 0; r < NRELS; r++) {
            offs[r] = off;
            off += ((cnt[r] + EPB - 1) / EPB) * EPB;  // pad each bucket to EPB
        }
    }
}

__global__ void k_scatter(const int* __restrict__ ety, const int* __restrict__ offs,
                          int* __restrict__ cursor, int* __restrict__ sorted) {
    __shared__ int hist[NRELS];
    __shared__ int basew[NRELS];
    int t = threadIdx.x;
    if (t < NRELS) hist[t] = 0;
    __syncthreads();
    int e = blockIdx.x * 256 + t;
    int r = -1, rank = 0;
    if (e < NEDGES) { r = ety[e]; rank = atomicAdd(&hist[r], 1); }
    __syncthreads();
    if (t < NRELS && hist[t] > 0) basew[t] = atomicAdd(&cursor[t], hist[t]);
    __syncthreads();
    if (e < NEDGES) sorted[offs[r] + basew[r] + rank] = e;
}

// ---------------- per-node attention projections: pd = Wa[:, :128]@h, ps = Wa[:,128:]@h ----------------
__global__ __launch_bounds__(256) void k_nodeproj(const float* __restrict__ h,
                                                  const float* __restrict__ W_a,
                                                  float* __restrict__ pd, float* __restrict__ ps) {
    int k = threadIdx.x & 63;
    int n = blockIdx.x * 4 + (threadIdx.x >> 6);
    if (n >= NNODES) return;
    const float4* hr = (const float4*)(h + (size_t)n * DIM);
    const float4* wd = (const float4*)(W_a + (size_t)k * TWOD);
    const float4* wsv = (const float4*)(W_a + (size_t)k * TWOD + DIM);
    float ad = 0.0f, as = 0.0f;
#pragma unroll
    for (int j = 0; j < DIM / 4; j++) {
        float4 hv = hr[j];
        float4 a = wd[j];
        float4 b = wsv[j];
        ad += a.x * hv.x + a.y * hv.y + a.z * hv.z + a.w * hv.w;
        as += b.x * hv.x + b.y * hv.y + b.z * hv.z + b.w * hv.w;
    }
    pd[(size_t)n * ADIM + k] = ad;
    ps[(size_t)n * ADIM + k] = as;
}

// ---------------- per-edge score + segment max (wave per edge) ----------------
__global__ __launch_bounds__(256) void k_score(const float* __restrict__ pd, const float* __restrict__ ps,
                                               const float* __restrict__ b_a, const float* __restrict__ ratt,
                                               const int* __restrict__ src, const int* __restrict__ dst,
                                               float* __restrict__ score, unsigned* __restrict__ smax_u) {
    int e = blockIdx.x * 4 + (threadIdx.x >> 6);
    int lane = threadIdx.x & 63;
    if (e >= NEDGES) return;
    int sn = src[e], dn = dst[e];
    float v = pd[(size_t)dn * ADIM + lane] + ps[(size_t)sn * ADIM + lane] + b_a[lane];
    v = v > 0.0f ? v : SLOPE * v;      // leaky_relu
    v *= ratt[lane];                   // rel_attention[0]
#pragma unroll
    for (int off = 32; off > 0; off >>= 1) v += __shfl_down(v, off);
    if (lane == 0) {
        score[e] = v;
        atomicMax(&smax_u[dn], enc_f(v));
    }
}

// ---------------- exp + segment denom ----------------
__global__ void k_expsum(const float* __restrict__ score, const int* __restrict__ dst,
                         const unsigned* __restrict__ smax_u, float* __restrict__ exv,
                         float* __restrict__ denom) {
    int e = blockIdx.x * 256 + threadIdx.x;
    if (e < NEDGES) {
        int dn = dst[e];
        float sm = dec_f(smax_u[dn]);
        float x = __expf(score[e] - sm);
        exv[e] = x;
        atomicAdd(&denom[dn], x);
    }
}

// ---------------- gates + messages (relation-uniform 64-edge blocks over sorted list) ----------------
__global__ __launch_bounds__(256) void k_gate_msg(
    const float* __restrict__ h, const float* __restrict__ relations,
    const int* __restrict__ sorted, const int* __restrict__ srcA, const int* __restrict__ dstA,
    const int* __restrict__ etyA, const float* __restrict__ exA, const float* __restrict__ denomA,
    float* __restrict__ hN) {
    __shared__ float rel_s[32][128];  // [dd][o]
    __shared__ float hc_s[64][32];    // [edge][dd]
    __shared__ int eid_s[64];
    __shared__ int dstn_s[64];
    __shared__ int srcn_s[64];
    __shared__ float att_s[64];
    __shared__ int r_s;

    const int t = threadIdx.x;
    const int base = blockIdx.x * EPB;

    if (t < EPB) {
        int e = sorted[base + t];
        eid_s[t] = e;
        if (e >= 0) {
            int dn = dstA[e], sn = srcA[e];
            dstn_s[t] = dn;
            srcn_s[t] = sn;
            att_s[t] = exA[e] / denomA[dn];
        } else {
            dstn_s[t] = 0;
            srcn_s[t] = 0;
            att_s[t] = 0.0f;
        }
        if (t == 0) r_s = (e >= 0) ? etyA[e] : 0;
    }
    __syncthreads();
    if (eid_s[0] < 0) return;  // fully-padded block (uniform exit)
    const int r = r_s;
    const int o = t & 127;
    const int ph = t >> 7;

    float acc[32];
#pragma unroll
    for (int j = 0; j < 32; j++) acc[j] = 0.0f;

    const float* relbase = relations + (size_t)r * TWOD * DIM;

    for (int d0 = 0; d0 < TWOD; d0 += 32) {
        // stage relation tile: rows d0..d0+31 are contiguous (d-major, o fastest)
        {
            const float4* rp = (const float4*)(relbase + (size_t)d0 * DIM);
            float4* rs = (float4*)&rel_s[0][0];
#pragma unroll
            for (int u = 0; u < 4; u++) rs[t + 256 * u] = rp[t + 256 * u];
        }
        // stage gathered h tile for the 64 edges (dst side for d0<128, src side after)
        {
            const int* nodes = (d0 < DIM) ? dstn_s : srcn_s;
            int col0 = d0 & (DIM - 1);
#pragma unroll
            for (int u = 0; u < 2; u++) {
                int vv = t + 256 * u;      // 0..511
                int i = vv >> 3, c4 = vv & 7;
                int node = nodes[i];
                float4 hv = *(const float4*)(h + (size_t)node * DIM + col0 + c4 * 4);
                *(float4*)&hc_s[i][c4 * 4] = hv;
            }
        }
        __syncthreads();

        float rv[32];
#pragma unroll
        for (int dd = 0; dd < 32; dd++) rv[dd] = rel_s[dd][o];
#pragma unroll
        for (int j = 0; j < 32; j++) {
            const float4* hp = (const float4*)&hc_s[ph * 32 + j][0];
#pragma unroll
            for (int q = 0; q < 8; q++) {
                float4 hv = hp[q];
                acc[j] += hv.x * rv[4 * q] + hv.y * rv[4 * q + 1] + hv.z * rv[4 * q + 2] + hv.w * rv[4 * q + 3];
            }
        }
        __syncthreads();
    }

    // epilogue: gate = sigmoid(acc); msg = src_h * attn * gate; atomic segment-sum into hN
    for (int j = 0; j < 32; j++) {
        int i = ph * 32 + j;
        int e = eid_s[i];
        if (e < 0) continue;
        float g = 1.0f / (1.0f + __expf(-acc[j]));
        float m = h[(size_t)srcn_s[i] * DIM + o] * att_s[i] * g;
        atomicAdd(&hN[(size_t)dstn_s[i] * DIM + o], m);
    }
}

// ---------------- output: out = leaky(W_lin @ [h ; h_N] + b_lin) ----------------
__global__ __launch_bounds__(256) void k_out(const float* __restrict__ h, const float* __restrict__ hN,
                                             const float* __restrict__ W_lin, const float* __restrict__ b_lin,
                                             float* __restrict__ out) {
    __shared__ float w_s[32][128];  // [dd][o] = W_lin[o][d0+dd]
    __shared__ float hc_s[64][32];  // [node][dd]
    const int t = threadIdx.x;
    const int o = t & 127;
    const int ph = t >> 7;
    const int nb = blockIdx.x * 64;

    float acc[32];
#pragma unroll
    for (int j = 0; j < 32; j++) acc[j] = 0.0f;

    for (int d0 = 0; d0 < TWOD; d0 += 32) {
        // stage W tile (transpose): W_lin is [128][256] row-major
        {
#pragma unroll
            for (int u = 0; u < 4; u++) {
                int v = t + 256 * u;           // 0..1023
                int oo = v >> 3, c4 = v & 7;
                float4 wv = *(const float4*)(W_lin + (size_t)oo * TWOD + d0 + c4 * 4);
                w_s[c4 * 4 + 0][oo] = wv.x;
                w_s[c4 * 4 + 1][oo] = wv.y;
                w_s[c4 * 4 + 2][oo] = wv.z;
                w_s[c4 * 4 + 3][oo] = wv.w;
            }
        }
        // stage node features: h for d0<128, hN after
        {
            const float* hsrc = (d0 < DIM) ? h : hN;
            int col0 = d0 & (DIM - 1);
#pragma unroll
            for (int u = 0; u < 2; u++) {
                int vv = t + 256 * u;
                int i = vv >> 3, c4 = vv & 7;
                int n = nb + i;
                if (n >= NNODES) n = NNODES - 1;
                *(float4*)&hc_s[i][c4 * 4] = *(const float4*)(hsrc + (size_t)n * DIM + col0 + c4 * 4);
            }
        }
        __syncthreads();

        float rv[32];
#pragma unroll
        for (int dd = 0; dd < 32; dd++) rv[dd] = w_s[dd][o];
#pragma unroll
        for (int j = 0; j < 32; j++) {
            const float4* hp = (const float4*)&hc_s[ph * 32 + j][0];
#pragma unroll
            for (int q = 0; q < 8; q++) {
                float4 hv = hp[q];
                acc[j] += hv.x * rv[4 * q] + hv.y * rv[4 * q + 1] + hv.z * rv[4 * q + 2] + hv.w * rv[4 * q + 3];
            }
        }
        __syncthreads();
    }

    float bl = b_lin[o];
    for (int j = 0; j < 32; j++) {
        int n = nb + ph * 32 + j;
        if (n < NNODES) {
            float val = acc[j] + bl;
            val = val > 0.0f ? val : SLOPE * val;
            out[(size_t)n * DIM + o] = val;
        }
    }
}

// ---------------- launcher ----------------
extern "C" void kernel_launch(void* const* d_in, const int* in_sizes, int n_in,
                              void* d_out, int out_size, void* d_ws, size_t ws_size,
                              hipStream_t stream) {
    const float* h     = (const float*)d_in[0];
    const float* rel   = (const float*)d_in[1];
    const float* ratt  = (const float*)d_in[2];  // [8][64]; row 0 used
    const float* W_a   = (const float*)d_in[3];
    const float* b_a   = (const float*)d_in[4];
    const float* W_lin = (const float*)d_in[5];
    const float* b_lin = (const float*)d_in[6];
    const int* src = (const int*)d_in[7];
    const int* dst = (const int*)d_in[8];
    const int* ety = (const int*)d_in[9];
    float* out = (float*)d_out;

    // workspace layout (~58 MB)
    float* wsf   = (float*)d_ws;
    float* score = wsf;                                   // E
    float* exv   = score + NEDGES;                        // E
    float* denom = exv + NEDGES;                          // N
    float* pd    = denom + NNODES;                        // N*64
    float* ps    = pd + (size_t)NNODES * ADIM;            // N*64
    float* hN    = ps + (size_t)NNODES * ADIM;            // N*128
    unsigned* smax_u = (unsigned*)(hN + (size_t)NNODES * DIM);  // N
    int* sorted  = (int*)(smax_u + NNODES);               // E + 1024
    int* cnts    = sorted + (NEDGES + 1024);              // cnt[8] + cursor[8]
    int* offs    = cnts + 16;                             // 8

    k_init<<<25000, 256, 0, stream>>>(hN, denom, smax_u, sorted, cnts);
    k_count<<<(NEDGES + 255) / 256, 256, 0, stream>>>(ety, cnts);
    k_prefix<<<1, 64, 0, stream>>>(cnts, offs);
    k_scatter<<<(NEDGES + 255) / 256, 256, 0, stream>>>(ety, offs, cnts + 8, sorted);
    k_nodeproj<<<NNODES / 4, 256, 0, stream>>>(h, W_a, pd, ps);
    k_score<<<NEDGES / 4, 256, 0, stream>>>(pd, ps, b_a, ratt, src, dst, score, smax_u);
    k_expsum<<<(NEDGES + 255) / 256, 256, 0, stream>>>(score, dst, smax_u, exv, denom);
    k_gate_msg<<<(NEDGES + 8 * EPB + EPB - 1) / EPB, 256, 0, stream>>>(
        h, rel, sorted, src, dst, ety, exv, denom, hN);
    k_out<<<(NNODES + 63) / 64, 256, 0, stream>>>(h, hN, W_lin, b_lin, out);
}

// Round 2
// 930.709 us; speedup vs baseline: 1.8993x; 1.8993x over previous
//
#include <hip/hip_runtime.h>
#include <cstdint>
#include <cstddef>

// ---------------- problem constants ----------------
constexpr int NNODES = 50000;
constexpr int NEDGES = 500000;
constexpr int NRELS  = 8;
constexpr int DIM    = 128;   // input/output dim
constexpr int ADIM   = 64;    // attention dim
constexpr int TWOD   = 256;   // 2*DIM
constexpr int EPB    = 64;    // edges per block in gate kernel
constexpr float SLOPE = 0.01f; // leaky_relu default slope

constexpr int XPITCH = TWOD + 8;  // LDS row pitch in bf16 elems (+8 => 2-way bank alias, free)

typedef __attribute__((ext_vector_type(8))) short short8;   // 8 bf16 = 4 VGPRs (MFMA A/B frag)
typedef __attribute__((ext_vector_type(4))) float floatx4;  // MFMA C/D frag

// fp32 -> bf16 round-to-nearest-even
__device__ __forceinline__ unsigned short f2bf(float f) {
    unsigned u = __float_as_uint(f);
    unsigned r = u + 0x7FFFu + ((u >> 16) & 1u);
    return (unsigned short)(r >> 16);
}
__device__ __forceinline__ float bf2f(unsigned short b) {
    return __uint_as_float(((unsigned)b) << 16);
}

// monotone float->uint encoding for atomicMax on floats
__device__ __forceinline__ unsigned enc_f(float f) {
    unsigned u = __float_as_uint(f);
    return (u & 0x80000000u) ? ~u : (u | 0x80000000u);
}
__device__ __forceinline__ float dec_f(unsigned k) {
    unsigned u = (k & 0x80000000u) ? (k & 0x7FFFFFFFu) : ~k;
    return __uint_as_float(u);
}

// ---------------- init: zero h_N/denom/counters, smax=0-key, sorted=-1 ----------------
__global__ void k_init(float* __restrict__ hN, float* __restrict__ denom,
                       unsigned* __restrict__ smax_u, int* __restrict__ sorted,
                       int* __restrict__ cnts /*16 ints: cnt[8]+cursor[8]*/) {
    int i = blockIdx.x * blockDim.x + threadIdx.x;
    int stride = gridDim.x * blockDim.x;
    for (int idx = i; idx < NNODES * DIM; idx += stride) hN[idx] = 0.0f;
    for (int idx = i; idx < NNODES; idx += stride) { denom[idx] = 0.0f; smax_u[idx] = 0u; }
    for (int idx = i; idx < NEDGES + 1024; idx += stride) sorted[idx] = -1;
    if (i < 16) cnts[i] = 0;
}

// ---------------- prep: relT[r][o][d] = bf16(rel[r][d][o]); Wl[o][d] = bf16(W_lin[o][d]) ----------------
__global__ void k_prep(const float* __restrict__ rel, const float* __restrict__ W_lin,
                       unsigned short* __restrict__ relT, unsigned short* __restrict__ Wl) {
    int idx = blockIdx.x * 256 + threadIdx.x;
    const int NREL_ELEMS = NRELS * TWOD * DIM;  // 262144
    if (idx < NREL_ELEMS) {
        int d = idx & 255;
        int o = (idx >> 8) & 127;
        int r = idx >> 15;
        relT[((size_t)r * DIM + o) * TWOD + d] = f2bf(rel[((size_t)r * TWOD + d) * DIM + o]);
    } else {
        int j = idx - NREL_ELEMS;
        if (j < DIM * TWOD) Wl[j] = f2bf(W_lin[j]);
    }
}

// ---------------- counting sort by etype ----------------
__global__ void k_count(const int* __restrict__ ety, int* __restrict__ cnt) {
    __shared__ int hist[NRELS];
    int t = threadIdx.x;
    if (t < NRELS) hist[t] = 0;
    __syncthreads();
    int e = blockIdx.x * 256 + t;
    if (e < NEDGES) atomicAdd(&hist[ety[e]], 1);
    __syncthreads();
    if (t < NRELS && hist[t] > 0) atomicAdd(&cnt[t], hist[t]);
}

__global__ void k_prefix(const int* __restrict__ cnt, int* __restrict__ offs) {
    if (blockIdx.x == 0 && threadIdx.x == 0) {
        int off = 0;
        for (int r = 0; r < NRELS; r++) {
            offs[r] = off;
            off += ((cnt[r] + EPB - 1) / EPB) * EPB;  // pad each bucket to EPB
        }
    }
}

__global__ void k_scatter(const int* __restrict__ ety, const int* __restrict__ offs,
                          int* __restrict__ cursor, int* __restrict__ sorted) {
    __shared__ int hist[NRELS];
    __shared__ int basew[NRELS];
    int t = threadIdx.x;
    if (t < NRELS) hist[t] = 0;
    __syncthreads();
    int e = blockIdx.x * 256 + t;
    int r = -1, rank = 0;
    if (e < NEDGES) { r = ety[e]; rank = atomicAdd(&hist[r], 1); }
    __syncthreads();
    if (t < NRELS && hist[t] > 0) basew[t] = atomicAdd(&cursor[t], hist[t]);
    __syncthreads();
    if (e < NEDGES) sorted[offs[r] + basew[r] + rank] = e;
}

// ---------------- per-node attention projections ----------------
__global__ __launch_bounds__(256) void k_nodeproj(const float* __restrict__ h,
                                                  const float* __restrict__ W_a,
                                                  float* __restrict__ pd, float* __restrict__ ps) {
    int k = threadIdx.x & 63;
    int n = blockIdx.x * 4 + (threadIdx.x >> 6);
    if (n >= NNODES) return;
    const float4* hr = (const float4*)(h + (size_t)n * DIM);
    const float4* wd = (const float4*)(W_a + (size_t)k * TWOD);
    const float4* wsv = (const float4*)(W_a + (size_t)k * TWOD + DIM);
    float ad = 0.0f, as = 0.0f;
#pragma unroll
    for (int j = 0; j < DIM / 4; j++) {
        float4 hv = hr[j];
        float4 a = wd[j];
        float4 b = wsv[j];
        ad += a.x * hv.x + a.y * hv.y + a.z * hv.z + a.w * hv.w;
        as += b.x * hv.x + b.y * hv.y + b.z * hv.z + b.w * hv.w;
    }
    pd[(size_t)n * ADIM + k] = ad;
    ps[(size_t)n * ADIM + k] = as;
}

// ---------------- per-edge score + segment max (wave per edge) ----------------
__global__ __launch_bounds__(256) void k_score(const float* __restrict__ pd, const float* __restrict__ ps,
                                               const float* __restrict__ b_a, const float* __restrict__ ratt,
                                               const int* __restrict__ src, const int* __restrict__ dst,
                                               float* __restrict__ score, unsigned* __restrict__ smax_u) {
    int e = blockIdx.x * 4 + (threadIdx.x >> 6);
    int lane = threadIdx.x & 63;
    if (e >= NEDGES) return;
    int sn = src[e], dn = dst[e];
    float v = pd[(size_t)dn * ADIM + lane] + ps[(size_t)sn * ADIM + lane] + b_a[lane];
    v = v > 0.0f ? v : SLOPE * v;      // leaky_relu
    v *= ratt[lane];                   // rel_attention[0]
#pragma unroll
    for (int off = 32; off > 0; off >>= 1) v += __shfl_down(v, off);
    if (lane == 0) {
        score[e] = v;
        atomicMax(&smax_u[dn], enc_f(v));
    }
}

// ---------------- exp + segment denom ----------------
__global__ void k_expsum(const float* __restrict__ score, const int* __restrict__ dst,
                         const unsigned* __restrict__ smax_u, float* __restrict__ exv,
                         float* __restrict__ denom) {
    int e = blockIdx.x * 256 + threadIdx.x;
    if (e < NEDGES) {
        int dn = dst[e];
        float sm = dec_f(smax_u[dn]);
        float x = __expf(score[e] - sm);
        exv[e] = x;
        atomicAdd(&denom[dn], x);
    }
}

// ---------------- gates + messages via MFMA bf16 ----------------
// Per block: 64 edges (relation-uniform) x 128 outputs, K=256 ([dst_h ; src_h]).
// X staged in LDS as bf16 (fp32->bf16 in flight); B = relT (bf16, [o][d]) preloaded
// into VGPRs per wave (16 frags); K-loop is ds_read_b128 + MFMA only.
__global__ __launch_bounds__(256) void k_gate_msg(
    const float* __restrict__ h, const unsigned short* __restrict__ relT,
    const int* __restrict__ sorted, const int* __restrict__ srcA, const int* __restrict__ dstA,
    const int* __restrict__ etyA, const float* __restrict__ exA, const float* __restrict__ denomA,
    float* __restrict__ hN) {
    __shared__ unsigned short Xs[EPB * XPITCH];  // 64 x 264 bf16 = 33792 B
    __shared__ int eid_s[EPB];
    __shared__ int dstn_s[EPB];
    __shared__ int srcn_s[EPB];
    __shared__ float att_s[EPB];
    __shared__ int r_s;

    const int t = threadIdx.x;
    const int base = blockIdx.x * EPB;

    if (t < EPB) {
        int e = sorted[base + t];
        eid_s[t] = e;
        if (e >= 0) {
            int dn = dstA[e], sn = srcA[e];
            dstn_s[t] = dn;
            srcn_s[t] = sn;
            att_s[t] = exA[e] / denomA[dn];
        } else {
            dstn_s[t] = 0;
            srcn_s[t] = 0;
            att_s[t] = 0.0f;
        }
        if (t == 0) r_s = (e >= 0) ? etyA[e] : 0;
    }
    __syncthreads();
    if (eid_s[0] < 0) return;  // fully-padded block (uniform)
    const int r = r_s;

    // stage X: 64 rows x 256 bf16; chunk = 8 bf16; 2048 chunks / 256 threads = 8 each
#pragma unroll
    for (int u = 0; u < 8; u++) {
        int v = u * 256 + t;
        int i = v >> 5;        // edge row
        int c = v & 31;        // chunk in row; c<16 -> dst half, else src half
        int node = (c < 16) ? dstn_s[i] : srcn_s[i];
        const float4* hp = (const float4*)(h + (size_t)node * DIM + (c & 15) * 8);
        float4 a = hp[0], b = hp[1];
        union { unsigned short us[8]; short8 s8; } pk;
        pk.us[0] = f2bf(a.x); pk.us[1] = f2bf(a.y); pk.us[2] = f2bf(a.z); pk.us[3] = f2bf(a.w);
        pk.us[4] = f2bf(b.x); pk.us[5] = f2bf(b.y); pk.us[6] = f2bf(b.z); pk.us[7] = f2bf(b.w);
        *(short8*)&Xs[i * XPITCH + c * 8] = pk.s8;
    }

    const int wave = t >> 6;
    const int lane = t & 63;
    const int q = lane >> 4;    // quad 0..3
    const int l16 = lane & 15;

    // preload B fragments: 2 N-tiles x 8 K-steps (wave-local output cols)
    short8 Bf[2][8];
#pragma unroll
    for (int nn = 0; nn < 2; nn++) {
        int o = (wave * 2 + nn) * 16 + l16;
        const unsigned short* bp = relT + ((size_t)r * DIM + o) * TWOD + q * 8;
#pragma unroll
        for (int ks = 0; ks < 8; ks++) Bf[nn][ks] = *(const short8*)(bp + ks * 32);
    }

    __syncthreads();

    floatx4 acc[4][2];
#pragma unroll
    for (int m = 0; m < 4; m++)
#pragma unroll
        for (int nn = 0; nn < 2; nn++) acc[m][nn] = (floatx4)(0.0f);

#pragma unroll
    for (int ks = 0; ks < 8; ks++) {
        short8 Af[4];
        const unsigned short* xb = &Xs[l16 * XPITCH + ks * 32 + q * 8];
#pragma unroll
        for (int m = 0; m < 4; m++) Af[m] = *(const short8*)(xb + m * 16 * XPITCH);
#pragma unroll
        for (int m = 0; m < 4; m++)
#pragma unroll
            for (int nn = 0; nn < 2; nn++)
                acc[m][nn] = __builtin_amdgcn_mfma_f32_16x16x32_bf16(Af[m], Bf[nn][ks], acc[m][nn], 0, 0, 0);
    }

    // epilogue: C/D layout col=lane&15, row=quad*4+reg
#pragma unroll
    for (int m = 0; m < 4; m++) {
        int ib = m * 16 + q * 4;
#pragma unroll
        for (int nn = 0; nn < 2; nn++) {
            int o = (wave * 2 + nn) * 16 + l16;
#pragma unroll
            for (int rg = 0; rg < 4; rg++) {
                int i = ib + rg;
                if (eid_s[i] < 0) continue;
                float g = 1.0f / (1.0f + __expf(-acc[m][nn][rg]));
                float sh = bf2f(Xs[i * XPITCH + DIM + o]);  // src_h[i][o]
                float msg = sh * att_s[i] * g;
                atomicAdd(&hN[(size_t)dstn_s[i] * DIM + o], msg);
            }
        }
    }
}

// ---------------- out = leaky(W_lin @ [h ; h_N] + b) via MFMA bf16 ----------------
__global__ __launch_bounds__(256) void k_out(const float* __restrict__ h, const float* __restrict__ hN,
                                             const unsigned short* __restrict__ Wl,
                                             const float* __restrict__ b_lin,
                                             float* __restrict__ out) {
    __shared__ unsigned short Xs[EPB * XPITCH];
    const int t = threadIdx.x;
    const int nb = blockIdx.x * 64;

#pragma unroll
    for (int u = 0; u < 8; u++) {
        int v = u * 256 + t;
        int i = v >> 5;
        int c = v & 31;
        int n = nb + i;
        if (n >= NNODES) n = NNODES - 1;
        const float* srcp = (c < 16) ? h : hN;
        const float4* hp = (const float4*)(srcp + (size_t)n * DIM + (c & 15) * 8);
        float4 a = hp[0], b = hp[1];
        union { unsigned short us[8]; short8 s8; } pk;
        pk.us[0] = f2bf(a.x); pk.us[1] = f2bf(a.y); pk.us[2] = f2bf(a.z); pk.us[3] = f2bf(a.w);
        pk.us[4] = f2bf(b.x); pk.us[5] = f2bf(b.y); pk.us[6] = f2bf(b.z); pk.us[7] = f2bf(b.w);
        *(short8*)&Xs[i * XPITCH + c * 8] = pk.s8;
    }

    const int wave = t >> 6;
    const int lane = t & 63;
    const int q = lane >> 4;
    const int l16 = lane & 15;

    short8 Bf[2][8];
#pragma unroll
    for (int nn = 0; nn < 2; nn++) {
        int o = (wave * 2 + nn) * 16 + l16;
        const unsigned short* bp = Wl + (size_t)o * TWOD + q * 8;
#pragma unroll
        for (int ks = 0; ks < 8; ks++) Bf[nn][ks] = *(const short8*)(bp + ks * 32);
    }

    __syncthreads();

    floatx4 acc[4][2];
#pragma unroll
    for (int m = 0; m < 4; m++)
#pragma unroll
        for (int nn = 0; nn < 2; nn++) acc[m][nn] = (floatx4)(0.0f);

#pragma unroll
    for (int ks = 0; ks < 8; ks++) {
        short8 Af[4];
        const unsigned short* xb = &Xs[l16 * XPITCH + ks * 32 + q * 8];
#pragma unroll
        for (int m = 0; m < 4; m++) Af[m] = *(const short8*)(xb + m * 16 * XPITCH);
#pragma unroll
        for (int m = 0; m < 4; m++)
#pragma unroll
            for (int nn = 0; nn < 2; nn++)
                acc[m][nn] = __builtin_amdgcn_mfma_f32_16x16x32_bf16(Af[m], Bf[nn][ks], acc[m][nn], 0, 0, 0);
    }

#pragma unroll
    for (int m = 0; m < 4; m++) {
        int ib = m * 16 + q * 4;
#pragma unroll
        for (int nn = 0; nn < 2; nn++) {
            int o = (wave * 2 + nn) * 16 + l16;
            float bl = b_lin[o];
#pragma unroll
            for (int rg = 0; rg < 4; rg++) {
                int n = nb + ib + rg;
                if (n < NNODES) {
                    float val = acc[m][nn][rg] + bl;
                    val = val > 0.0f ? val : SLOPE * val;
                    out[(size_t)n * DIM + o] = val;
                }
            }
        }
    }
}

// ---------------- launcher ----------------
extern "C" void kernel_launch(void* const* d_in, const int* in_sizes, int n_in,
                              void* d_out, int out_size, void* d_ws, size_t ws_size,
                              hipStream_t stream) {
    const float* h     = (const float*)d_in[0];
    const float* rel   = (const float*)d_in[1];
    const float* ratt  = (const float*)d_in[2];  // [8][64]; row 0 used
    const float* W_a   = (const float*)d_in[3];
    const float* b_a   = (const float*)d_in[4];
    const float* W_lin = (const float*)d_in[5];
    const float* b_lin = (const float*)d_in[6];
    const int* src = (const int*)d_in[7];
    const int* dst = (const int*)d_in[8];
    const int* ety = (const int*)d_in[9];
    float* out = (float*)d_out;

    // workspace layout (~51.5 MB)
    float* wsf   = (float*)d_ws;
    float* score = wsf;                                   // E
    float* exv   = score + NEDGES;                        // E
    float* denom = exv + NEDGES;                          // N
    float* pd    = denom + NNODES;                        // N*64
    float* ps    = pd + (size_t)NNODES * ADIM;            // N*64
    float* hN    = ps + (size_t)NNODES * ADIM;            // N*128
    unsigned* smax_u = (unsigned*)(hN + (size_t)NNODES * DIM);  // N
    int* sorted  = (int*)(smax_u + NNODES);               // E + 1024
    int* cnts    = sorted + (NEDGES + 1024);              // cnt[8] + cursor[8]
    int* offs    = cnts + 16;                             // 8
    unsigned short* relT = (unsigned short*)(offs + 8);   // 8*128*256 bf16
    unsigned short* Wl   = relT + (size_t)NRELS * DIM * TWOD;  // 128*256 bf16

    k_init<<<25000, 256, 0, stream>>>(hN, denom, smax_u, sorted, cnts);
    k_prep<<<(NRELS * TWOD * DIM + DIM * TWOD + 255) / 256, 256, 0, stream>>>(rel, W_lin, relT, Wl);
    k_count<<<(NEDGES + 255) / 256, 256, 0, stream>>>(ety, cnts);
    k_prefix<<<1, 64, 0, stream>>>(cnts, offs);
    k_scatter<<<(NEDGES + 255) / 256, 256, 0, stream>>>(ety, offs, cnts + 8, sorted);
    k_nodeproj<<<NNODES / 4, 256, 0, stream>>>(h, W_a, pd, ps);
    k_score<<<NEDGES / 4, 256, 0, stream>>>(pd, ps, b_a, ratt, src, dst, score, smax_u);
    k_expsum<<<(NEDGES + 255) / 256, 256, 0, stream>>>(score, dst, smax_u, exv, denom);
    k_gate_msg<<<(NEDGES + 8 * EPB + EPB - 1) / EPB, 256, 0, stream>>>(
        h, relT, sorted, src, dst, ety, exv, denom, hN);
    k_out<<<(NNODES + 63) / 64, 256, 0, stream>>>(h, hN, Wl, b_lin, out);
}

// Round 3
// 553.395 us; speedup vs baseline: 3.1943x; 1.6818x over previous
//
#include <hip/hip_runtime.h>
#include <cstdint>
#include <cstddef>

// ---------------- problem constants ----------------
constexpr int NNODES = 50000;
constexpr int NEDGES = 500000;
constexpr int NRELS  = 8;
constexpr int DIM    = 128;   // input/output dim
constexpr int ADIM   = 64;    // attention dim
constexpr int TWOD   = 256;   // 2*DIM
constexpr int EPB    = 64;    // edges per block in gate kernel
constexpr float SLOPE = 0.01f; // leaky_relu default slope

constexpr int XPITCH = TWOD + 8;   // LDS row pitch (bf16 elems) for K=256 kernels
constexpr int PPITCH = DIM + 8;    // LDS row pitch for K=128 kernel

typedef __attribute__((ext_vector_type(8))) short short8;   // 8 bf16 = 4 VGPRs (MFMA A/B frag)
typedef __attribute__((ext_vector_type(4))) float floatx4;  // MFMA C/D frag

// fp32 -> bf16 round-to-nearest-even
__device__ __forceinline__ unsigned short f2bf(float f) {
    unsigned u = __float_as_uint(f);
    unsigned r = u + 0x7FFFu + ((u >> 16) & 1u);
    return (unsigned short)(r >> 16);
}
__device__ __forceinline__ float bf2f(unsigned short b) {
    return __uint_as_float(((unsigned)b) << 16);
}

// monotone float->uint encoding for atomicMax on floats
__device__ __forceinline__ unsigned enc_f(float f) {
    unsigned u = __float_as_uint(f);
    return (u & 0x80000000u) ? ~u : (u | 0x80000000u);
}
__device__ __forceinline__ float dec_f(unsigned k) {
    unsigned u = (k & 0x80000000u) ? (k & 0x7FFFFFFFu) : ~k;
    return __uint_as_float(u);
}

// ---------------- init ----------------
__global__ void k_init(float* __restrict__ hN, float* __restrict__ denom,
                       unsigned* __restrict__ smax_u, int* __restrict__ sorted,
                       int* __restrict__ cnts /*16 ints: cnt[8]+cursor[8]*/) {
    int i = blockIdx.x * blockDim.x + threadIdx.x;
    int stride = gridDim.x * blockDim.x;
    for (int idx = i; idx < NNODES * DIM; idx += stride) hN[idx] = 0.0f;
    for (int idx = i; idx < NNODES; idx += stride) { denom[idx] = 0.0f; smax_u[idx] = 0u; }
    for (int idx = i; idx < NEDGES + 1024; idx += stride) sorted[idx] = -1;
    if (i < 16) cnts[i] = 0;
}

// ---------------- prep: bf16 weight tables ----------------
// relT[r][o][d] = rel[r][d][o];  Wl[o][d] = W_lin[o][d];
// Wa2[o][d] (o<64: W_a[o][d] "pd side"; o>=64: W_a[o-64][128+d] "ps side")
__global__ void k_prep(const float* __restrict__ rel, const float* __restrict__ W_lin,
                       const float* __restrict__ W_a,
                       unsigned short* __restrict__ relT, unsigned short* __restrict__ Wl,
                       unsigned short* __restrict__ Wa2) {
    int idx = blockIdx.x * 256 + threadIdx.x;
    const int NREL_ELEMS = NRELS * TWOD * DIM;  // 262144
    const int WL_ELEMS = DIM * TWOD;            // 32768
    const int WA2_ELEMS = DIM * DIM;            // 16384
    if (idx < NREL_ELEMS) {
        int d = idx & 255;
        int o = (idx >> 8) & 127;
        int r = idx >> 15;
        relT[((size_t)r * DIM + o) * TWOD + d] = f2bf(rel[((size_t)r * TWOD + d) * DIM + o]);
    } else if (idx < NREL_ELEMS + WL_ELEMS) {
        int j = idx - NREL_ELEMS;
        Wl[j] = f2bf(W_lin[j]);
    } else if (idx < NREL_ELEMS + WL_ELEMS + WA2_ELEMS) {
        int j = idx - NREL_ELEMS - WL_ELEMS;
        int d = j & 127, o = j >> 7;
        float v = (o < ADIM) ? W_a[(size_t)o * TWOD + d] : W_a[(size_t)(o - ADIM) * TWOD + DIM + d];
        Wa2[j] = f2bf(v);
    }
}

// ---------------- counting sort by etype ----------------
__global__ void k_count(const int* __restrict__ ety, int* __restrict__ cnt) {
    __shared__ int hist[NRELS];
    int t = threadIdx.x;
    if (t < NRELS) hist[t] = 0;
    __syncthreads();
    int e = blockIdx.x * 256 + t;
    if (e < NEDGES) atomicAdd(&hist[ety[e]], 1);
    __syncthreads();
    if (t < NRELS && hist[t] > 0) atomicAdd(&cnt[t], hist[t]);
}

__global__ void k_prefix(const int* __restrict__ cnt, int* __restrict__ offs) {
    if (blockIdx.x == 0 && threadIdx.x == 0) {
        int off = 0;
        for (int r = 0; r < NRELS; r++) {
            offs[r] = off;
            off += ((cnt[r] + EPB - 1) / EPB) * EPB;  // pad each bucket to EPB
        }
    }
}

__global__ void k_scatter(const int* __restrict__ ety, const int* __restrict__ offs,
                          int* __restrict__ cursor, int* __restrict__ sorted) {
    __shared__ int hist[NRELS];
    __shared__ int basew[NRELS];
    int t = threadIdx.x;
    if (t < NRELS) hist[t] = 0;
    __syncthreads();
    int e = blockIdx.x * 256 + t;
    int r = -1, rank = 0;
    if (e < NEDGES) { r = ety[e]; rank = atomicAdd(&hist[r], 1); }
    __syncthreads();
    if (t < NRELS && hist[t] > 0) basew[t] = atomicAdd(&cursor[t], hist[t]);
    __syncthreads();
    if (e < NEDGES) sorted[offs[r] + basew[r] + rank] = e;
}

// ---------------- node attention projections via MFMA: proj = h @ Wa2^T ----------------
// proj[n][o] : o<64 = pd[n][o], o>=64 = ps[n][o-64].  [50000,128]@[128,128], K=128.
__global__ __launch_bounds__(256) void k_nodeproj(const float* __restrict__ h,
                                                  const unsigned short* __restrict__ Wa2,
                                                  float* __restrict__ proj) {
    __shared__ unsigned short Xs[EPB * PPITCH];  // 64 x 136 bf16 = 17408 B
    const int t = threadIdx.x;
    const int nb = blockIdx.x * 64;

    // stage 64 rows x 128 bf16; 1024 chunks of 8 / 256 threads = 4 each
#pragma unroll
    for (int u = 0; u < 4; u++) {
        int v = u * 256 + t;
        int i = v >> 4;       // row
        int c = v & 15;       // chunk
        int n = nb + i;
        if (n >= NNODES) n = NNODES - 1;
        const float4* hp = (const float4*)(h + (size_t)n * DIM + c * 8);
        float4 a = hp[0], b = hp[1];
        union { unsigned short us[8]; short8 s8; } pk;
        pk.us[0] = f2bf(a.x); pk.us[1] = f2bf(a.y); pk.us[2] = f2bf(a.z); pk.us[3] = f2bf(a.w);
        pk.us[4] = f2bf(b.x); pk.us[5] = f2bf(b.y); pk.us[6] = f2bf(b.z); pk.us[7] = f2bf(b.w);
        *(short8*)&Xs[i * PPITCH + c * 8] = pk.s8;
    }

    const int wave = t >> 6;
    const int lane = t & 63;
    const int q = lane >> 4;
    const int l16 = lane & 15;

    short8 Bf[2][4];
#pragma unroll
    for (int nn = 0; nn < 2; nn++) {
        int o = (wave * 2 + nn) * 16 + l16;
        const unsigned short* bp = Wa2 + (size_t)o * DIM + q * 8;
#pragma unroll
        for (int ks = 0; ks < 4; ks++) Bf[nn][ks] = *(const short8*)(bp + ks * 32);
    }

    __syncthreads();

    floatx4 acc[4][2];
#pragma unroll
    for (int m = 0; m < 4; m++)
#pragma unroll
        for (int nn = 0; nn < 2; nn++) acc[m][nn] = (floatx4)(0.0f);

#pragma unroll
    for (int ks = 0; ks < 4; ks++) {
        short8 Af[4];
        const unsigned short* xb = &Xs[l16 * PPITCH + ks * 32 + q * 8];
#pragma unroll
        for (int m = 0; m < 4; m++) Af[m] = *(const short8*)(xb + m * 16 * PPITCH);
#pragma unroll
        for (int m = 0; m < 4; m++)
#pragma unroll
            for (int nn = 0; nn < 2; nn++)
                acc[m][nn] = __builtin_amdgcn_mfma_f32_16x16x32_bf16(Af[m], Bf[nn][ks], acc[m][nn], 0, 0, 0);
    }

#pragma unroll
    for (int m = 0; m < 4; m++) {
        int ib = m * 16 + q * 4;
#pragma unroll
        for (int nn = 0; nn < 2; nn++) {
            int o = (wave * 2 + nn) * 16 + l16;
#pragma unroll
            for (int rg = 0; rg < 4; rg++) {
                int n = nb + ib + rg;
                if (n < NNODES) proj[(size_t)n * DIM + o] = acc[m][nn][rg];
            }
        }
    }
}

// ---------------- per-edge score + segment max (wave per edge) ----------------
__global__ __launch_bounds__(256) void k_score(const float* __restrict__ proj,
                                               const float* __restrict__ b_a, const float* __restrict__ ratt,
                                               const int* __restrict__ src, const int* __restrict__ dst,
                                               float* __restrict__ score, unsigned* __restrict__ smax_u) {
    int e = blockIdx.x * 4 + (threadIdx.x >> 6);
    int lane = threadIdx.x & 63;
    if (e >= NEDGES) return;
    int sn = src[e], dn = dst[e];
    float v = proj[(size_t)dn * DIM + lane] + proj[(size_t)sn * DIM + ADIM + lane] + b_a[lane];
    v = v > 0.0f ? v : SLOPE * v;      // leaky_relu
    v *= ratt[lane];                   // rel_attention[0]
#pragma unroll
    for (int off = 32; off > 0; off >>= 1) v += __shfl_down(v, off);
    if (lane == 0) {
        score[e] = v;
        atomicMax(&smax_u[dn], enc_f(v));
    }
}

// ---------------- exp + segment denom ----------------
__global__ void k_expsum(const float* __restrict__ score, const int* __restrict__ dst,
                         const unsigned* __restrict__ smax_u, float* __restrict__ exv,
                         float* __restrict__ denom) {
    int e = blockIdx.x * 256 + threadIdx.x;
    if (e < NEDGES) {
        int dn = dst[e];
        float sm = dec_f(smax_u[dn]);
        float x = __expf(score[e] - sm);
        exv[e] = x;
        atomicAdd(&denom[dn], x);
    }
}

// ---------------- gates + messages via MFMA bf16 ----------------
__global__ __launch_bounds__(256) void k_gate_msg(
    const float* __restrict__ h, const unsigned short* __restrict__ relT,
    const int* __restrict__ sorted, const int* __restrict__ srcA, const int* __restrict__ dstA,
    const int* __restrict__ etyA, const float* __restrict__ exA, const float* __restrict__ denomA,
    float* __restrict__ hN) {
    __shared__ unsigned short Xs[EPB * XPITCH];  // 64 x 264 bf16 = 33792 B
    __shared__ int eid_s[EPB];
    __shared__ int dstn_s[EPB];
    __shared__ int srcn_s[EPB];
    __shared__ float att_s[EPB];
    __shared__ int r_s;

    const int t = threadIdx.x;
    const int base = blockIdx.x * EPB;

    if (t < EPB) {
        int e = sorted[base + t];
        eid_s[t] = e;
        if (e >= 0) {
            int dn = dstA[e], sn = srcA[e];
            dstn_s[t] = dn;
            srcn_s[t] = sn;
            att_s[t] = exA[e] / denomA[dn];
        } else {
            dstn_s[t] = 0;
            srcn_s[t] = 0;
            att_s[t] = 0.0f;
        }
        if (t == 0) r_s = (e >= 0) ? etyA[e] : 0;
    }
    __syncthreads();
    if (eid_s[0] < 0) return;  // fully-padded block (uniform)
    const int r = r_s;

    // stage X: 64 rows x 256 bf16
#pragma unroll
    for (int u = 0; u < 8; u++) {
        int v = u * 256 + t;
        int i = v >> 5;        // edge row
        int c = v & 31;        // chunk; c<16 -> dst half, else src half
        int node = (c < 16) ? dstn_s[i] : srcn_s[i];
        const float4* hp = (const float4*)(h + (size_t)node * DIM + (c & 15) * 8);
        float4 a = hp[0], b = hp[1];
        union { unsigned short us[8]; short8 s8; } pk;
        pk.us[0] = f2bf(a.x); pk.us[1] = f2bf(a.y); pk.us[2] = f2bf(a.z); pk.us[3] = f2bf(a.w);
        pk.us[4] = f2bf(b.x); pk.us[5] = f2bf(b.y); pk.us[6] = f2bf(b.z); pk.us[7] = f2bf(b.w);
        *(short8*)&Xs[i * XPITCH + c * 8] = pk.s8;
    }

    const int wave = t >> 6;
    const int lane = t & 63;
    const int q = lane >> 4;
    const int l16 = lane & 15;

    short8 Bf[2][8];
#pragma unroll
    for (int nn = 0; nn < 2; nn++) {
        int o = (wave * 2 + nn) * 16 + l16;
        const unsigned short* bp = relT + ((size_t)r * DIM + o) * TWOD + q * 8;
#pragma unroll
        for (int ks = 0; ks < 8; ks++) Bf[nn][ks] = *(const short8*)(bp + ks * 32);
    }

    __syncthreads();

    floatx4 acc[4][2];
#pragma unroll
    for (int m = 0; m < 4; m++)
#pragma unroll
        for (int nn = 0; nn < 2; nn++) acc[m][nn] = (floatx4)(0.0f);

#pragma unroll
    for (int ks = 0; ks < 8; ks++) {
        short8 Af[4];
        const unsigned short* xb = &Xs[l16 * XPITCH + ks * 32 + q * 8];
#pragma unroll
        for (int m = 0; m < 4; m++) Af[m] = *(const short8*)(xb + m * 16 * XPITCH);
#pragma unroll
        for (int m = 0; m < 4; m++)
#pragma unroll
            for (int nn = 0; nn < 2; nn++)
                acc[m][nn] = __builtin_amdgcn_mfma_f32_16x16x32_bf16(Af[m], Bf[nn][ks], acc[m][nn], 0, 0, 0);
    }

    // epilogue: C/D layout col=lane&15, row=quad*4+reg
#pragma unroll
    for (int m = 0; m < 4; m++) {
        int ib = m * 16 + q * 4;
#pragma unroll
        for (int nn = 0; nn < 2; nn++) {
            int o = (wave * 2 + nn) * 16 + l16;
#pragma unroll
            for (int rg = 0; rg < 4; rg++) {
                int i = ib + rg;
                if (eid_s[i] < 0) continue;
                float g = 1.0f / (1.0f + __expf(-acc[m][nn][rg]));
                float sh = bf2f(Xs[i * XPITCH + DIM + o]);  // src_h[i][o]
                float msg = sh * att_s[i] * g;
                atomicAdd(&hN[(size_t)dstn_s[i] * DIM + o], msg);
            }
        }
    }
}

// ---------------- out = leaky(W_lin @ [h ; h_N] + b) via MFMA bf16 ----------------
__global__ __launch_bounds__(256) void k_out(const float* __restrict__ h, const float* __restrict__ hN,
                                             const unsigned short* __restrict__ Wl,
                                             const float* __restrict__ b_lin,
                                             float* __restrict__ out) {
    __shared__ unsigned short Xs[EPB * XPITCH];
    const int t = threadIdx.x;
    const int nb = blockIdx.x * 64;

#pragma unroll
    for (int u = 0; u < 8; u++) {
        int v = u * 256 + t;
        int i = v >> 5;
        int c = v & 31;
        int n = nb + i;
        if (n >= NNODES) n = NNODES - 1;
        const float* srcp = (c < 16) ? h : hN;
        const float4* hp = (const float4*)(srcp + (size_t)n * DIM + (c & 15) * 8);
        float4 a = hp[0], b = hp[1];
        union { unsigned short us[8]; short8 s8; } pk;
        pk.us[0] = f2bf(a.x); pk.us[1] = f2bf(a.y); pk.us[2] = f2bf(a.z); pk.us[3] = f2bf(a.w);
        pk.us[4] = f2bf(b.x); pk.us[5] = f2bf(b.y); pk.us[6] = f2bf(b.z); pk.us[7] = f2bf(b.w);
        *(short8*)&Xs[i * XPITCH + c * 8] = pk.s8;
    }

    const int wave = t >> 6;
    const int lane = t & 63;
    const int q = lane >> 4;
    const int l16 = lane & 15;

    short8 Bf[2][8];
#pragma unroll
    for (int nn = 0; nn < 2; nn++) {
        int o = (wave * 2 + nn) * 16 + l16;
        const unsigned short* bp = Wl + (size_t)o * TWOD + q * 8;
#pragma unroll
        for (int ks = 0; ks < 8; ks++) Bf[nn][ks] = *(const short8*)(bp + ks * 32);
    }

    __syncthreads();

    floatx4 acc[4][2];
#pragma unroll
    for (int m = 0; m < 4; m++)
#pragma unroll
        for (int nn = 0; nn < 2; nn++) acc[m][nn] = (floatx4)(0.0f);

#pragma unroll
    for (int ks = 0; ks < 8; ks++) {
        short8 Af[4];
        const unsigned short* xb = &Xs[l16 * XPITCH + ks * 32 + q * 8];
#pragma unroll
        for (int m = 0; m < 4; m++) Af[m] = *(const short8*)(xb + m * 16 * XPITCH);
#pragma unroll
        for (int m = 0; m < 4; m++)
#pragma unroll
            for (int nn = 0; nn < 2; nn++)
                acc[m][nn] = __builtin_amdgcn_mfma_f32_16x16x32_bf16(Af[m], Bf[nn][ks], acc[m][nn], 0, 0, 0);
    }

#pragma unroll
    for (int m = 0; m < 4; m++) {
        int ib = m * 16 + q * 4;
#pragma unroll
        for (int nn = 0; nn < 2; nn++) {
            int o = (wave * 2 + nn) * 16 + l16;
            float bl = b_lin[o];
#pragma unroll
            for (int rg = 0; rg < 4; rg++) {
                int n = nb + ib + rg;
                if (n < NNODES) {
                    float val = acc[m][nn][rg] + bl;
                    val = val > 0.0f ? val : SLOPE * val;
                    out[(size_t)n * DIM + o] = val;
                }
            }
        }
    }
}

// ---------------- launcher ----------------
extern "C" void kernel_launch(void* const* d_in, const int* in_sizes, int n_in,
                              void* d_out, int out_size, void* d_ws, size_t ws_size,
                              hipStream_t stream) {
    const float* h     = (const float*)d_in[0];
    const float* rel   = (const float*)d_in[1];
    const float* ratt  = (const float*)d_in[2];  // [8][64]; row 0 used
    const float* W_a   = (const float*)d_in[3];
    const float* b_a   = (const float*)d_in[4];
    const float* W_lin = (const float*)d_in[5];
    const float* b_lin = (const float*)d_in[6];
    const int* src = (const int*)d_in[7];
    const int* dst = (const int*)d_in[8];
    const int* ety = (const int*)d_in[9];
    float* out = (float*)d_out;

    // workspace layout (~59 MB)
    float* wsf   = (float*)d_ws;
    float* score = wsf;                                   // E
    float* exv   = score + NEDGES;                        // E
    float* denom = exv + NEDGES;                          // N
    float* proj  = denom + NNODES;                        // N*128 (pd||ps)
    float* hN    = proj + (size_t)NNODES * DIM;           // N*128
    unsigned* smax_u = (unsigned*)(hN + (size_t)NNODES * DIM);  // N
    int* sorted  = (int*)(smax_u + NNODES);               // E + 1024
    int* cnts    = sorted + (NEDGES + 1024);              // cnt[8] + cursor[8]
    int* offs    = cnts + 16;                             // 8
    unsigned short* relT = (unsigned short*)(offs + 8);   // 8*128*256 bf16
    unsigned short* Wl   = relT + (size_t)NRELS * DIM * TWOD;  // 128*256 bf16
    unsigned short* Wa2  = Wl + (size_t)DIM * TWOD;       // 128*128 bf16

    k_init<<<25000, 256, 0, stream>>>(hN, denom, smax_u, sorted, cnts);
    k_prep<<<(NRELS * TWOD * DIM + DIM * TWOD + DIM * DIM + 255) / 256, 256, 0, stream>>>(
        rel, W_lin, W_a, relT, Wl, Wa2);
    k_count<<<(NEDGES + 255) / 256, 256, 0, stream>>>(ety, cnts);
    k_prefix<<<1, 64, 0, stream>>>(cnts, offs);
    k_scatter<<<(NEDGES + 255) / 256, 256, 0, stream>>>(ety, offs, cnts + 8, sorted);
    k_nodeproj<<<(NNODES + 63) / 64, 256, 0, stream>>>(h, Wa2, proj);
    k_score<<<NEDGES / 4, 256, 0, stream>>>(proj, b_a, ratt, src, dst, score, smax_u);
    k_expsum<<<(NEDGES + 255) / 256, 256, 0, stream>>>(score, dst, smax_u, exv, denom);
    k_gate_msg<<<(NEDGES + 8 * EPB + EPB - 1) / EPB, 256, 0, stream>>>(
        h, relT, sorted, src, dst, ety, exv, denom, hN);
    k_out<<<(NNODES + 63) / 64, 256, 0, stream>>>(h, hN, Wl, b_lin, out);
}